// Round 20
// baseline (60.675 us; speedup 1.0000x reference)
//
#include <hip/hip_runtime.h>
#include <stdint.h>

// B=1, N=2048, D=1024, h=16, e=64; chunks of 64 tokens -> 32 chunks/head
#define NTOK 2048
#define NCH 32

typedef __attribute__((ext_vector_type(8))) short bf16x8;
typedef __attribute__((ext_vector_type(8))) unsigned short ushort8v;
typedef __attribute__((ext_vector_type(4))) float f32x4;

__device__ __forceinline__ unsigned short f2bf(float f) {
  unsigned u = __float_as_uint(f);
  u += 0x7fffu + ((u >> 16) & 1u);   // RNE
  return (unsigned short)(u >> 16);
}
__device__ __forceinline__ float bf2f(unsigned short s) {
  return __uint_as_float(((unsigned)s) << 16);
}

// ---- fused input prep: x -> bf16; W -> Wt bf16 transposed + HEAD-MAJOR permuted ----
// Wt row layout: [head h][q(64) | v(64) | k(64)]  (row = 192h + 64*region + j)
__global__ __launch_bounds__(256) void k_prep_inputs(const float* __restrict__ x,
                                                     unsigned short* __restrict__ xb,
                                                     const float* __restrict__ W,
                                                     unsigned short* __restrict__ Wt) {
  int bid = blockIdx.x;
  if (bid < 2048) {
    int i = (bid * 256 + threadIdx.x) * 4;
    float4 v = *(const float4*)(x + i);
    ushort4 o = { f2bf(v.x), f2bf(v.y), f2bf(v.z), f2bf(v.w) };
    *(ushort4*)(xb + i) = o;
  } else {
    __shared__ float tile[32][33];
    int id = bid - 2048;            // 3072 blocks: bx in [0,96), by in [0,32)
    int bx = id % 96, by = id / 96;
    int tx = threadIdx.x & 31, ty = threadIdx.x >> 5;
    int c0 = bx * 32;
    int r0 = by * 32;
#pragma unroll
    for (int j = 0; j < 32; j += 8)
      tile[ty + j][tx] = W[(size_t)(r0 + ty + j) * 3072 + c0 + tx];
    __syncthreads();
#pragma unroll
    for (int j = 0; j < 32; j += 8) {
      int oc = c0 + ty + j;          // original W column
      int rowp = ((oc & 1023) >> 6) * 192 + (oc >> 10) * 64 + (oc & 63);
      Wt[(size_t)rowp * 1024 + r0 + tx] = f2bf(tile[tx][ty + j]);
    }
  }
}

// ---- GEMM 2048x3072 (head-major Wt), 128x192 tile, 768 thr (12 waves of 32x64), BK=64 ----
// A-operand DIRECT global->register (double-buffered 1 tile ahead, no LDS for A);
// B in 3-buffer single-barrier LDS pipeline; uniform counted vmcnt(2).
// LDS ops/CU/tile: 184 -> 120. grid (16,16) = 1 block/CU; LDS 72 KB.
__global__ __launch_bounds__(768, 1) void k_gemm_fused(const unsigned short* __restrict__ xb,
                                                       const unsigned short* __restrict__ wt,
                                                       const float* __restrict__ bias,
                                                       unsigned short* __restrict__ qh,
                                                       unsigned short* __restrict__ kh,
                                                       unsigned short* __restrict__ vt,
                                                       unsigned short* __restrict__ Sc,
                                                       float* __restrict__ zc) {
  __shared__ __align__(16) unsigned short Bs[3][192][64];    // 3 x 24 KB
  const int t = threadIdx.x;           // 0..767
  const int lane = t & 63;
  const int wave = t >> 6;             // 0..11
  const int wr = wave / 3;             // 0..3 (32-row block)
  const int wc = wave % 3;             // 0..2 (64-col block) == region (q/v/k)
  const int rowBase = blockIdx.y * 128;
  const int colBase = blockIdx.x * 192;
  const int fr = lane & 15;
  const int khalf = lane >> 4;         // 0..3

  // B staging: 1536 x 16B chunks over 768 threads = 2 each (XOR-swizzled source)
  const unsigned short* gB[2];
  char* lB[2];
#pragma unroll
  for (int j = 0; j < 2; ++j) {
    int idx = t + j * 768;
    int row = idx >> 3;
    int slot = (idx & 7) ^ (row & 7);
    gB[j] = wt + (size_t)(colBase + row) * 1024 + slot * 8;
    lB[j] = (char*)Bs + idx * 16;
  }
  // A direct-to-register base pointers (lane-resolved fragment addresses)
  const unsigned short* aptr[2];
#pragma unroll
  for (int m = 0; m < 2; ++m)
    aptr[m] = xb + (size_t)(rowBase + wr * 32 + m * 16 + fr) * 1024 + khalf * 8;

#define STGB(buf, kt0) do {                                                               \
    _Pragma("unroll")                                                                     \
    for (int j_ = 0; j_ < 2; ++j_)                                                        \
      __builtin_amdgcn_global_load_lds(                                                   \
          (const __attribute__((address_space(1))) void*)(gB[j_] + (kt0) * 64),           \
          (__attribute__((address_space(3))) void*)(lB[j_] + (buf) * 24576), 16, 0, 0);   \
  } while (0)

#define LOADA(dst, kt0) do {                                                              \
    _Pragma("unroll")                                                                     \
    for (int m_ = 0; m_ < 2; ++m_) {                                                      \
      dst[m_][0] = *(const bf16x8*)(aptr[m_] + (kt0) * 64);                               \
      dst[m_][1] = *(const bf16x8*)(aptr[m_] + (kt0) * 64 + 32);                          \
    }                                                                                     \
  } while (0)

#define VM2()   asm volatile("s_waitcnt vmcnt(2)" ::: "memory")
#define VM0()   asm volatile("s_waitcnt vmcnt(0)" ::: "memory")
#define LGKM0() asm volatile("s_waitcnt lgkmcnt(0)" ::: "memory")
#define BAR()   __builtin_amdgcn_s_barrier()

  f32x4 acc[2][4] = {};
  const int fs0 = khalf ^ (fr & 7);   // swizzled slot for ks=0; ks=1 is fs0^4

#define LOADB(cur, bff) do {                                                              \
    _Pragma("unroll")                                                                     \
    for (int n = 0; n < 4; ++n) {                                                         \
      const unsigned short* r = &Bs[cur][wc * 64 + n * 16 + fr][0];                       \
      bff[n][0] = *(const bf16x8*)(r + fs0 * 8);                                          \
      bff[n][1] = *(const bf16x8*)(r + (fs0 ^ 4) * 8);                                    \
    }                                                                                     \
  } while (0)

#define DO_MFMA(af, bff) do {                                                             \
    _Pragma("unroll")                                                                     \
    for (int m = 0; m < 2; ++m)                                                           \
      _Pragma("unroll")                                                                   \
      for (int n = 0; n < 4; ++n) {                                                       \
        acc[m][n] = __builtin_amdgcn_mfma_f32_16x16x32_bf16(af[m][0], bff[n][0], acc[m][n], 0, 0, 0); \
        acc[m][n] = __builtin_amdgcn_mfma_f32_16x16x32_bf16(af[m][1], bff[n][1], acc[m][n], 0, 0, 0); \
      }                                                                                   \
  } while (0)

  bf16x8 aA[2][2], aB[2][2];
  LOADA(aA, 0);                        // A(0) issued FIRST (queue-order invariant)
  STGB(0, 0);
  STGB(1, 1);
#pragma unroll 1
  for (int kp = 0; kp < 8; ++kp) {
    {  // even ktile: compute with aA, prefetch A(t+1) into aB
      const int ktile = 2 * kp;
      const int cur = ktile % 3;
      VM2();                           // A(t) + B(t) complete; newest 2 (B(t+1)) in flight
      BAR();
      __builtin_amdgcn_sched_barrier(0);
      LOADA(aB, ktile + 1);
      __builtin_amdgcn_sched_barrier(0);
      if (ktile < 14) STGB((ktile + 2) % 3, ktile + 2);
      bf16x8 bff[4][2];
      LOADB(cur, bff);
      LGKM0();
      __builtin_amdgcn_sched_barrier(0);
      __builtin_amdgcn_s_setprio(1);
      DO_MFMA(aA, bff);
      __builtin_amdgcn_s_setprio(0);
    }
    {  // odd ktile: compute with aB, prefetch A(t+1) into aA
      const int ktile = 2 * kp + 1;
      const int cur = ktile % 3;
      if (ktile < 15) { VM2(); }
      else            { VM0(); }
      BAR();
      __builtin_amdgcn_sched_barrier(0);
      if (ktile < 15) LOADA(aA, ktile + 1);
      __builtin_amdgcn_sched_barrier(0);
      if (ktile < 14) STGB((ktile + 2) % 3, ktile + 2);
      bf16x8 bff[4][2];
      LOADB(cur, bff);
      LGKM0();
      __builtin_amdgcn_sched_barrier(0);
      __builtin_amdgcn_s_setprio(1);
      DO_MFMA(aB, bff);
      __builtin_amdgcn_s_setprio(0);
    }
  }
#undef STGB
#undef LOADA
#undef LOADB
#undef DO_MFMA

  // all waves' Bs reads are drained (each passed its LGKM0) -> safe to alias Bs
  BAR();
  unsigned short (*Lkv)[2][64][72] =
      reinterpret_cast<unsigned short (*)[2][64][72]>(&Bs[0][0][0]);  // [chunk][k/v][e][tok]

  // ---- fused epilogue: region = wc, head = blockIdx.x (R16/R19-verified) ----
  const int g2 = khalf;               // C row group: row = 4*g2+i
  const int ocol = lane & 15;         // C col within 16-block
  const int region = wc;              // 0=q 1=v 2=k
  const int h = blockIdx.x;
  const int r0 = rowBase + wr * 32;   // global token base of this wave
  const int cch = r0 >> 6;            // chunk index
  const int cq = wr >> 1;             // chunk-local (0/1) within block
  const int lbase = (wr & 1) * 32;    // chunk-local row base
  float bv[4];
#pragma unroll
  for (int n = 0; n < 4; ++n) bv[n] = bias[region * 1024 + h * 64 + 16 * n + ocol];

  if (region == 0) {                  // q: softmax over e (in-wave), *0.125
#pragma unroll
    for (int m = 0; m < 2; ++m) {
#pragma unroll
      for (int i = 0; i < 4; ++i) {
        float v[4];
#pragma unroll
        for (int n = 0; n < 4; ++n) v[n] = acc[m][n][i] + bv[n];
        float mx = fmaxf(fmaxf(v[0], v[1]), fmaxf(v[2], v[3]));
#pragma unroll
        for (int off = 1; off <= 8; off <<= 1) mx = fmaxf(mx, __shfl_xor(mx, off));
        float s = 0.f;
#pragma unroll
        for (int n = 0; n < 4; ++n) { v[n] = __expf(v[n] - mx); s += v[n]; }
#pragma unroll
        for (int off = 1; off <= 8; off <<= 1) s += __shfl_xor(s, off);
        float inv = 0.125f / s;
        int tok = r0 + 16 * m + 4 * g2 + i;
        unsigned short* qrow = qh + ((size_t)h * NTOK + tok) * 64;
#pragma unroll
        for (int n = 0; n < 4; ++n) qrow[16 * n + ocol] = f2bf(v[n] * inv);
      }
    }
  } else if (region == 1) {           // v: write vt global + LDS tile
    unsigned short* vb = vt + (size_t)(h * NCH + cch) * 4096;
#pragma unroll
    for (int m = 0; m < 2; ++m) {
      int tl = lbase + 16 * m + 4 * g2;
#pragma unroll
      for (int n = 0; n < 4; ++n) {
        int e = 16 * n + ocol;
        ushort4 p = { f2bf(acc[m][n][0] + bv[n]), f2bf(acc[m][n][1] + bv[n]),
                      f2bf(acc[m][n][2] + bv[n]), f2bf(acc[m][n][3] + bv[n]) };
        *(ushort4*)&vb[(size_t)e * 64 + tl] = p;
        *(ushort4*)&Lkv[cq][1][e][tl] = p;
      }
    }
  } else {                            // k: exp, write kh global + LDS tile
#pragma unroll
    for (int m = 0; m < 2; ++m) {
      int tl = lbase + 16 * m + 4 * g2;
#pragma unroll
      for (int n = 0; n < 4; ++n) {
        int e = 16 * n + ocol;
        float kv[4];
#pragma unroll
        for (int i = 0; i < 4; ++i) kv[i] = __expf(acc[m][n][i] + bv[n]);
        ushort4 p = { f2bf(kv[0]), f2bf(kv[1]), f2bf(kv[2]), f2bf(kv[3]) };
        *(ushort4*)&Lkv[cq][0][e][tl] = p;
#pragma unroll
        for (int i = 0; i < 4; ++i)
          kh[((size_t)h * NTOK + r0 + 16 * m + 4 * g2 + i) * 64 + e] = p[i];
      }
    }
  }
  BAR();   // K/V LDS tiles complete

  // ---- in-block chunk sums (R16-verified body on LDS tiles) ----
  if (wave < 8) {
    const int q = wave >> 2;          // chunk-local 0/1
    const int w4 = wave & 3;          // d-block
    const int cchg = 2 * blockIdx.y + q;
    bf16x8 ka[2];
#pragma unroll
    for (int ks = 0; ks < 2; ++ks)
      ka[ks] = *(const bf16x8*)&Lkv[q][0][16 * w4 + fr][32 * ks + khalf * 8];
    f32x4 s4[4] = {};
#pragma unroll
    for (int nb = 0; nb < 4; ++nb)
#pragma unroll
      for (int ks = 0; ks < 2; ++ks) {
        bf16x8 vf = *(const bf16x8*)&Lkv[q][1][16 * nb + fr][32 * ks + khalf * 8];
        s4[nb] = __builtin_amdgcn_mfma_f32_16x16x32_bf16(ka[ks], vf, s4[nb], 0, 0, 0);
      }
    unsigned short* so = Sc + (size_t)(h * NCH + cchg) * 4096;   // [e'][d] bf16
#pragma unroll
    for (int nb = 0; nb < 4; ++nb) {
      ushort4 o = { f2bf(s4[nb][0]), f2bf(s4[nb][1]), f2bf(s4[nb][2]), f2bf(s4[nb][3]) };
      *(ushort4*)&so[(size_t)(16 * nb + fr) * 64 + 16 * w4 + 4 * g2] = o;
    }
    if (w4 == 0) {
      float z = 0.f;
#pragma unroll
      for (int j = 0; j < 8; ++j) {
        bf16x8 kv = *(const bf16x8*)&Lkv[q][0][lane][j * 8];
#pragma unroll
        for (int e = 0; e < 8; ++e) z += bf2f((unsigned short)kv[e]);
      }
      zc[(size_t)(h * NCH + cchg) * 64 + lane] = z;
    }
  }
}

// ---- exclusive prefix over chunks, element-parallel; bf16 in, bf16 out (f32 accum) ----
__global__ __launch_bounds__(256) void k_scan(const unsigned short* __restrict__ Sc,
                                              unsigned short* __restrict__ Sp,
                                              const float* __restrict__ zc,
                                              float* __restrict__ zp) {
  int b = blockIdx.x;
  if (b < 256) {
    int tg = b * 256 + threadIdx.x;
    int h = tg >> 12, e = tg & 4095;
    float run = 0.f;
    for (int c = 0; c < NCH; ++c) {
      size_t idx = (size_t)(h * NCH + c) * 4096 + e;
      float v = bf2f(Sc[idx]);
      Sp[idx] = f2bf(run);
      run += v;
    }
  } else {
#pragma unroll
    for (int j = 0; j < 4; ++j) {
      int s = threadIdx.x + j * 256;
      int h = s >> 6, d = s & 63;
      float run = 0.f;
      for (int c = 0; c < NCH; ++c) {
        size_t idx = (size_t)(h * NCH + c) * 64 + d;
        zp[idx] = run;
        run += zc[idx];
      }
    }
  }
}

// ---- attention: O = M(QK^T) V + Q S_prev, denom fused; all MFMA ----
__global__ __launch_bounds__(256) void k_attn(const unsigned short* __restrict__ qh,
                                              const unsigned short* __restrict__ kh,
                                              const unsigned short* __restrict__ vt,
                                              const unsigned short* __restrict__ Sp,
                                              const float* __restrict__ zp,
                                              float* __restrict__ out) {
  int h = blockIdx.x >> 5, c = blockIdx.x & 31;
  __shared__ __align__(16) unsigned short Qs[64][72], Ks[64][72], Vts[64][72], Sts[64][72], Ams[64][72];
  __shared__ __align__(16) float zs[64];
  __shared__ float denom[64];
  int t = threadIdx.x, lane = t & 63, w = t >> 6;
  int fr = lane & 15, g = lane >> 4, fko = g * 8;
  const unsigned short* qg = qh + ((size_t)h * NTOK + c * 64) * 64;
  const unsigned short* kg = kh + ((size_t)h * NTOK + c * 64) * 64;
  const unsigned short* vg = vt + (size_t)(h * NCH + c) * 4096;
  const unsigned short* sg = Sp + (size_t)(h * NCH + c) * 4096;
  for (int s = t; s < 512; s += 256) {
    int r = s >> 3, c8 = (s & 7) * 8;
    *(ushort8v*)&Qs[r][c8]  = *(const ushort8v*)&qg[r * 64 + c8];
    *(ushort8v*)&Ks[r][c8]  = *(const ushort8v*)&kg[r * 64 + c8];
    *(ushort8v*)&Vts[r][c8] = *(const ushort8v*)&vg[r * 64 + c8];
    *(ushort8v*)&Sts[r][c8] = *(const ushort8v*)&sg[r * 64 + c8];
  }
  if (t < 64) zs[t] = zp[(size_t)h * NCH * 64 + (size_t)c * 64 + t];
  __syncthreads();

  // step 1: A = Q K^T
  bf16x8 qa[2];
#pragma unroll
  for (int ks = 0; ks < 2; ++ks) qa[ks] = *(const bf16x8*)&Qs[16 * w + fr][32 * ks + fko];
  f32x4 a1[4] = {};
#pragma unroll
  for (int mb = 0; mb < 4; ++mb)
#pragma unroll
    for (int ks = 0; ks < 2; ++ks) {
      bf16x8 kf = *(const bf16x8*)&Ks[16 * mb + fr][32 * ks + fko];
      a1[mb] = __builtin_amdgcn_mfma_f32_16x16x32_bf16(qa[ks], kf, a1[mb], 0, 0, 0);
    }
#pragma unroll
  for (int i = 0; i < 4; ++i) {
    int n = 16 * w + 4 * g + i;
    ushort4 qv4 = *(const ushort4*)&Qs[n][fr * 4];
    float4  zv4 = *(const float4*)&zs[fr * 4];
    float rs = bf2f(qv4.x) * zv4.x + bf2f(qv4.y) * zv4.y +
               bf2f(qv4.z) * zv4.z + bf2f(qv4.w) * zv4.w;
#pragma unroll
    for (int mb = 0; mb < 4; ++mb) {
      int m = 16 * mb + fr;
      float v = (m <= n) ? a1[mb][i] : 0.f;
      a1[mb][i] = v;
      rs += v;
      Ams[n][16 * mb + fr] = f2bf(v);
    }
#pragma unroll
    for (int off = 1; off <= 8; off <<= 1) rs += __shfl_xor(rs, off);
    if (fr == 0) denom[n] = rs + 1.25e-7f;   // eps * sum(q) = 1e-6 * 0.125
  }
  __syncthreads();

  // step 2: O^T[e'][n] = Vt·A + St·Q
  bf16x8 xa[4];
#pragma unroll
  for (int ks = 0; ks < 2; ++ks) {
    xa[ks]     = *(const bf16x8*)&Vts[16 * w + fr][32 * ks + fko];
    xa[2 + ks] = *(const bf16x8*)&Sts[16 * w + fr][32 * ks + fko];
  }
  f32x4 o4[4] = {};
#pragma unroll
  for (int nb = 0; nb < 4; ++nb)
#pragma unroll
    for (int ks = 0; ks < 2; ++ks) {
      bf16x8 afr = *(const bf16x8*)&Ams[16 * nb + fr][32 * ks + fko];
      o4[nb] = __builtin_amdgcn_mfma_f32_16x16x32_bf16(xa[ks], afr, o4[nb], 0, 0, 0);
      bf16x8 qfr = *(const bf16x8*)&Qs[16 * nb + fr][32 * ks + fko];
      o4[nb] = __builtin_amdgcn_mfma_f32_16x16x32_bf16(xa[2 + ks], qfr, o4[nb], 0, 0, 0);
    }
#pragma unroll
  for (int nb = 0; nb < 4; ++nb) {
    int n = 16 * nb + fr;
    float dv = denom[n];
    float4 res = { o4[nb][0] / dv, o4[nb][1] / dv, o4[nb][2] / dv, o4[nb][3] / dv };
    *(float4*)&out[(size_t)(c * 64 + n) * 1024 + h * 64 + 16 * w + 4 * g] = res;
  }
}

extern "C" void kernel_launch(void* const* d_in, const int* in_sizes, int n_in,
                              void* d_out, int out_size, void* d_ws, size_t ws_size,
                              hipStream_t stream) {
  (void)in_sizes; (void)n_in; (void)out_size; (void)ws_size;
  const float* x = (const float*)d_in[0];
  const float* W = (const float*)d_in[1];
  const float* b = (const float*)d_in[2];
  char* ws = (char*)d_ws;

  const size_t MB = 1024 * 1024;
  unsigned short* xb = (unsigned short*)(ws + 0);        // 4 MB
  unsigned short* Wt = (unsigned short*)(ws + 4 * MB);   // 6 MB
  unsigned short* qh = (unsigned short*)(ws + 10 * MB);  // 4 MB
  unsigned short* kh = (unsigned short*)(ws + 14 * MB);  // 4 MB
  unsigned short* vt = (unsigned short*)(ws + 18 * MB);  // 4 MB
  unsigned short* Sc = (unsigned short*)(ws + 22 * MB);  // 4 MB (bf16 chunk sums)
  unsigned short* Sp = (unsigned short*)(ws + 26 * MB);  // 4 MB (bf16 exclusive prefix)
  float*          zc = (float*)(ws + 30 * MB);           // 128 KB
  float*          zp = (float*)(ws + 30 * MB + 131072);  // 128 KB

  k_prep_inputs<<<dim3(5120), dim3(256), 0, stream>>>(x, xb, W, Wt);
  k_gemm_fused<<<dim3(16, 16), dim3(768), 0, stream>>>(xb, Wt, b, qh, kh, vt, Sc, zc);
  k_scan<<<dim3(257), dim3(256), 0, stream>>>(Sc, Sp, zc, zp);
  k_attn<<<dim3(512), dim3(256), 0, stream>>>(qh, kh, vt, Sp, zp, (float*)d_out);
}

// Round 21
// 43.828 us; speedup vs baseline: 1.3844x; 1.3844x over previous
//
#include <hip/hip_runtime.h>
#include <stdint.h>

// B=1, N=2048, D=1024, h=16, e=64; chunks of 64 tokens -> 32 chunks/head
#define NTOK 2048
#define NCH 32

typedef __attribute__((ext_vector_type(8))) short bf16x8;
typedef __attribute__((ext_vector_type(8))) unsigned short ushort8v;
typedef __attribute__((ext_vector_type(4))) float f32x4;

__device__ __forceinline__ unsigned short f2bf(float f) {
  unsigned u = __float_as_uint(f);
  u += 0x7fffu + ((u >> 16) & 1u);   // RNE
  return (unsigned short)(u >> 16);
}
__device__ __forceinline__ float bf2f(unsigned short s) {
  return __uint_as_float(((unsigned)s) << 16);
}

// ---- fused input prep: x -> bf16; W -> Wt bf16 transposed + HEAD-MAJOR permuted ----
// Wt row layout: [head h][q(64) | v(64) | k(64)]  (row = 192h + 64*region + j)
__global__ __launch_bounds__(256) void k_prep_inputs(const float* __restrict__ x,
                                                     unsigned short* __restrict__ xb,
                                                     const float* __restrict__ W,
                                                     unsigned short* __restrict__ Wt) {
  int bid = blockIdx.x;
  if (bid < 2048) {
    int i = (bid * 256 + threadIdx.x) * 4;
    float4 v = *(const float4*)(x + i);
    ushort4 o = { f2bf(v.x), f2bf(v.y), f2bf(v.z), f2bf(v.w) };
    *(ushort4*)(xb + i) = o;
  } else {
    __shared__ float tile[32][33];
    int id = bid - 2048;            // 3072 blocks: bx in [0,96), by in [0,32)
    int bx = id % 96, by = id / 96;
    int tx = threadIdx.x & 31, ty = threadIdx.x >> 5;
    int c0 = bx * 32;
    int r0 = by * 32;
#pragma unroll
    for (int j = 0; j < 32; j += 8)
      tile[ty + j][tx] = W[(size_t)(r0 + ty + j) * 3072 + c0 + tx];
    __syncthreads();
#pragma unroll
    for (int j = 0; j < 32; j += 8) {
      int oc = c0 + ty + j;          // original W column
      int rowp = ((oc & 1023) >> 6) * 192 + (oc >> 10) * 64 + (oc & 63);
      Wt[(size_t)rowp * 1024 + r0 + tx] = f2bf(tile[tx][ty + j]);
    }
  }
}

// ---- GEMM 2048x3072 (head-major Wt), 128x192 tile, 768 thr (12 waves of 32x64), BK=64 ----
// R16-verified: 3-buffer single-barrier counted-vmcnt loop; in-block chunk sums.
__global__ __launch_bounds__(768, 1) void k_gemm_fused(const unsigned short* __restrict__ xb,
                                                       const unsigned short* __restrict__ wt,
                                                       const float* __restrict__ bias,
                                                       unsigned short* __restrict__ qh,
                                                       unsigned short* __restrict__ kh,
                                                       unsigned short* __restrict__ vt,
                                                       unsigned short* __restrict__ Sc,
                                                       float* __restrict__ zc) {
  __shared__ __align__(16) unsigned short As[3][128][64];    // 3 x 16 KB (reused for K/V tiles)
  __shared__ __align__(16) unsigned short Bs[3][192][64];    // 3 x 24 KB
  const int t = threadIdx.x;           // 0..767
  const int lane = t & 63;
  const int wave = t >> 6;             // 0..11
  const int wr = wave / 3;             // 0..3 (32-row block)
  const int wc = wave % 3;             // 0..2 (64-col block) == region (q/v/k)
  const int rowBase = blockIdx.y * 128;
  const int colBase = blockIdx.x * 192;
  const int fr = lane & 15;
  const int khalf = lane >> 4;         // 0..3

  const bool isA = t < 256;            // wave-uniform
  const int nL = isA ? 4 : 3;
  const int bstr = isA ? 16384 : 24576;
  const unsigned short* gsrc[4];
  char* ldst[4];
#pragma unroll
  for (int j = 0; j < 4; ++j) {
    int idx = isA ? (t + j * 256) : (t - 256 + j * 512);
    if (j >= nL) idx = 0;
    int row = idx >> 3;
    int ssl = (idx & 7) ^ (row & 7);   // XOR swizzle (inverse on source)
    gsrc[j] = (isA ? xb + (size_t)(rowBase + row) * 1024
                   : wt + (size_t)(colBase + row) * 1024) + ssl * 8;
    ldst[j] = (isA ? (char*)As : (char*)Bs) + idx * 16;
  }

#define STG(buf, kt0) do {                                                                \
    _Pragma("unroll")                                                                     \
    for (int j_ = 0; j_ < 4; ++j_)                                                        \
      if (j_ < nL)                                                                        \
        __builtin_amdgcn_global_load_lds(                                                 \
            (const __attribute__((address_space(1))) void*)(gsrc[j_] + (kt0) * 64),       \
            (__attribute__((address_space(3))) void*)(ldst[j_] + (buf) * bstr), 16, 0, 0);\
  } while (0)

#define VMW_STEADY() do {                                                                 \
    if (isA) asm volatile("s_waitcnt vmcnt(4)" ::: "memory");                             \
    else     asm volatile("s_waitcnt vmcnt(3)" ::: "memory");                             \
  } while (0)
#define VMCNT0() asm volatile("s_waitcnt vmcnt(0)" ::: "memory")
#define LGKM0()  asm volatile("s_waitcnt lgkmcnt(0)" ::: "memory")
#define BAR()    __builtin_amdgcn_s_barrier()

  f32x4 acc[2][4] = {};
  const int fs0 = khalf ^ (fr & 7);   // swizzled slot for ks=0; ks=1 is fs0^4

#define LOAD_FRAGS(cur, af, bff) do {                                                     \
    _Pragma("unroll")                                                                     \
    for (int m = 0; m < 2; ++m) {                                                         \
      const unsigned short* r = &As[cur][wr * 32 + m * 16 + fr][0];                       \
      af[m][0] = *(const bf16x8*)(r + fs0 * 8);                                           \
      af[m][1] = *(const bf16x8*)(r + (fs0 ^ 4) * 8);                                     \
    }                                                                                     \
    _Pragma("unroll")                                                                     \
    for (int n = 0; n < 4; ++n) {                                                         \
      const unsigned short* r = &Bs[cur][wc * 64 + n * 16 + fr][0];                       \
      bff[n][0] = *(const bf16x8*)(r + fs0 * 8);                                          \
      bff[n][1] = *(const bf16x8*)(r + (fs0 ^ 4) * 8);                                    \
    }                                                                                     \
  } while (0)

#define DO_MFMA(af, bff) do {                                                             \
    _Pragma("unroll")                                                                     \
    for (int m = 0; m < 2; ++m)                                                           \
      _Pragma("unroll")                                                                   \
      for (int n = 0; n < 4; ++n) {                                                       \
        acc[m][n] = __builtin_amdgcn_mfma_f32_16x16x32_bf16(af[m][0], bff[n][0], acc[m][n], 0, 0, 0); \
        acc[m][n] = __builtin_amdgcn_mfma_f32_16x16x32_bf16(af[m][1], bff[n][1], acc[m][n], 0, 0, 0); \
      }                                                                                   \
  } while (0)

  STG(0, 0);
  STG(1, 1);
#pragma unroll 1
  for (int ktile = 0; ktile < 16; ++ktile) {
    const int cur = ktile % 3;
    if (ktile < 15) { VMW_STEADY(); }
    else            { VMCNT0(); }
    BAR();
    __builtin_amdgcn_sched_barrier(0);
    bf16x8 af[2][2], bff[4][2];
    LOAD_FRAGS(cur, af, bff);
    if (ktile < 14) STG((ktile + 2) % 3, ktile + 2);
    LGKM0();
    __builtin_amdgcn_sched_barrier(0);
    __builtin_amdgcn_s_setprio(1);
    DO_MFMA(af, bff);
    __builtin_amdgcn_s_setprio(0);
  }
#undef STG
#undef LOAD_FRAGS
#undef DO_MFMA

  // all waves' As reads are drained (each passed its own LGKM0) -> safe to alias As
  BAR();
  unsigned short (*Lkv)[2][64][72] =
      reinterpret_cast<unsigned short (*)[2][64][72]>(&As[0][0][0]);  // [chunk][k/v][e][tok]

  // ---- fused epilogue: region = wc, head = blockIdx.x ----
  const int g2 = khalf;               // C row group: row = 4*g2+i
  const int ocol = lane & 15;         // C col within 16-block
  const int region = wc;              // 0=q 1=v 2=k
  const int h = blockIdx.x;
  const int r0 = rowBase + wr * 32;   // global token base of this wave
  const int cch = r0 >> 6;            // chunk index
  const int cq = wr >> 1;             // chunk-local (0/1) within block
  const int lbase = (wr & 1) * 32;    // chunk-local row base
  float bv[4];
#pragma unroll
  for (int n = 0; n < 4; ++n) bv[n] = bias[region * 1024 + h * 64 + 16 * n + ocol];

  if (region == 0) {                  // q: softmax over e (in-wave), *0.125
#pragma unroll
    for (int m = 0; m < 2; ++m) {
#pragma unroll
      for (int i = 0; i < 4; ++i) {
        float v[4];
#pragma unroll
        for (int n = 0; n < 4; ++n) v[n] = acc[m][n][i] + bv[n];
        float mx = fmaxf(fmaxf(v[0], v[1]), fmaxf(v[2], v[3]));
#pragma unroll
        for (int off = 1; off <= 8; off <<= 1) mx = fmaxf(mx, __shfl_xor(mx, off));
        float s = 0.f;
#pragma unroll
        for (int n = 0; n < 4; ++n) { v[n] = __expf(v[n] - mx); s += v[n]; }
#pragma unroll
        for (int off = 1; off <= 8; off <<= 1) s += __shfl_xor(s, off);
        float inv = 0.125f / s;
        int tok = r0 + 16 * m + 4 * g2 + i;
        unsigned short* qrow = qh + ((size_t)h * NTOK + tok) * 64;
#pragma unroll
        for (int n = 0; n < 4; ++n) qrow[16 * n + ocol] = f2bf(v[n] * inv);
      }
    }
  } else if (region == 1) {           // v: write vt global + LDS tile
    unsigned short* vb = vt + (size_t)(h * NCH + cch) * 4096;
#pragma unroll
    for (int m = 0; m < 2; ++m) {
      int tl = lbase + 16 * m + 4 * g2;
#pragma unroll
      for (int n = 0; n < 4; ++n) {
        int e = 16 * n + ocol;
        ushort4 p = { f2bf(acc[m][n][0] + bv[n]), f2bf(acc[m][n][1] + bv[n]),
                      f2bf(acc[m][n][2] + bv[n]), f2bf(acc[m][n][3] + bv[n]) };
        *(ushort4*)&vb[(size_t)e * 64 + tl] = p;
        *(ushort4*)&Lkv[cq][1][e][tl] = p;
      }
    }
  } else {                            // k: exp, write kh global + LDS tile
#pragma unroll
    for (int m = 0; m < 2; ++m) {
      int tl = lbase + 16 * m + 4 * g2;
#pragma unroll
      for (int n = 0; n < 4; ++n) {
        int e = 16 * n + ocol;
        float kv[4];
#pragma unroll
        for (int i = 0; i < 4; ++i) kv[i] = __expf(acc[m][n][i] + bv[n]);
        ushort4 p = { f2bf(kv[0]), f2bf(kv[1]), f2bf(kv[2]), f2bf(kv[3]) };
        *(ushort4*)&Lkv[cq][0][e][tl] = p;
#pragma unroll
        for (int i = 0; i < 4; ++i)
          kh[((size_t)h * NTOK + r0 + 16 * m + 4 * g2 + i) * 64 + e] = p[i];
      }
    }
  }
  BAR();   // K/V LDS tiles complete

  // ---- in-block chunk sums (verbatim k_chunk_sums body on LDS tiles) ----
  if (wave < 8) {
    const int q = wave >> 2;          // chunk-local 0/1
    const int w4 = wave & 3;          // d-block
    const int cchg = 2 * blockIdx.y + q;
    bf16x8 ka[2];
#pragma unroll
    for (int ks = 0; ks < 2; ++ks)
      ka[ks] = *(const bf16x8*)&Lkv[q][0][16 * w4 + fr][32 * ks + khalf * 8];
    f32x4 s4[4] = {};
#pragma unroll
    for (int nb = 0; nb < 4; ++nb)
#pragma unroll
      for (int ks = 0; ks < 2; ++ks) {
        bf16x8 vf = *(const bf16x8*)&Lkv[q][1][16 * nb + fr][32 * ks + khalf * 8];
        s4[nb] = __builtin_amdgcn_mfma_f32_16x16x32_bf16(ka[ks], vf, s4[nb], 0, 0, 0);
      }
    unsigned short* so = Sc + (size_t)(h * NCH + cchg) * 4096;   // [e'][d] bf16
#pragma unroll
    for (int nb = 0; nb < 4; ++nb) {
      ushort4 o = { f2bf(s4[nb][0]), f2bf(s4[nb][1]), f2bf(s4[nb][2]), f2bf(s4[nb][3]) };
      *(ushort4*)&so[(size_t)(16 * nb + fr) * 64 + 16 * w4 + 4 * g2] = o;
    }
    if (w4 == 0) {
      float z = 0.f;
#pragma unroll
      for (int j = 0; j < 8; ++j) {
        bf16x8 kv = *(const bf16x8*)&Lkv[q][0][lane][j * 8];
#pragma unroll
        for (int e = 0; e < 8; ++e) z += bf2f((unsigned short)kv[e]);
      }
      zc[(size_t)(h * NCH + cchg) * 64 + lane] = z;
    }
  }
}

// ---- exclusive prefix over chunks, element-parallel; bf16 in, bf16 out (f32 accum) ----
__global__ __launch_bounds__(256) void k_scan(const unsigned short* __restrict__ Sc,
                                              unsigned short* __restrict__ Sp,
                                              const float* __restrict__ zc,
                                              float* __restrict__ zp) {
  int b = blockIdx.x;
  if (b < 256) {
    int tg = b * 256 + threadIdx.x;
    int h = tg >> 12, e = tg & 4095;
    float run = 0.f;
    for (int c = 0; c < NCH; ++c) {
      size_t idx = (size_t)(h * NCH + c) * 4096 + e;
      float v = bf2f(Sc[idx]);
      Sp[idx] = f2bf(run);
      run += v;
    }
  } else {
#pragma unroll
    for (int j = 0; j < 4; ++j) {
      int s = threadIdx.x + j * 256;
      int h = s >> 6, d = s & 63;
      float run = 0.f;
      for (int c = 0; c < NCH; ++c) {
        size_t idx = (size_t)(h * NCH + c) * 64 + d;
        zp[idx] = run;
        run += zc[idx];
      }
    }
  }
}

// ---- attention: O = M(QK^T) V + Q S_prev, denom fused; all MFMA ----
__global__ __launch_bounds__(256) void k_attn(const unsigned short* __restrict__ qh,
                                              const unsigned short* __restrict__ kh,
                                              const unsigned short* __restrict__ vt,
                                              const unsigned short* __restrict__ Sp,
                                              const float* __restrict__ zp,
                                              float* __restrict__ out) {
  int h = blockIdx.x >> 5, c = blockIdx.x & 31;
  __shared__ __align__(16) unsigned short Qs[64][72], Ks[64][72], Vts[64][72], Sts[64][72], Ams[64][72];
  __shared__ __align__(16) float zs[64];
  __shared__ float denom[64];
  int t = threadIdx.x, lane = t & 63, w = t >> 6;
  int fr = lane & 15, g = lane >> 4, fko = g * 8;
  const unsigned short* qg = qh + ((size_t)h * NTOK + c * 64) * 64;
  const unsigned short* kg = kh + ((size_t)h * NTOK + c * 64) * 64;
  const unsigned short* vg = vt + (size_t)(h * NCH + c) * 4096;
  const unsigned short* sg = Sp + (size_t)(h * NCH + c) * 4096;
  for (int s = t; s < 512; s += 256) {
    int r = s >> 3, c8 = (s & 7) * 8;
    *(ushort8v*)&Qs[r][c8]  = *(const ushort8v*)&qg[r * 64 + c8];
    *(ushort8v*)&Ks[r][c8]  = *(const ushort8v*)&kg[r * 64 + c8];
    *(ushort8v*)&Vts[r][c8] = *(const ushort8v*)&vg[r * 64 + c8];
    *(ushort8v*)&Sts[r][c8] = *(const ushort8v*)&sg[r * 64 + c8];
  }
  if (t < 64) zs[t] = zp[(size_t)h * NCH * 64 + (size_t)c * 64 + t];
  __syncthreads();

  // step 1: A = Q K^T
  bf16x8 qa[2];
#pragma unroll
  for (int ks = 0; ks < 2; ++ks) qa[ks] = *(const bf16x8*)&Qs[16 * w + fr][32 * ks + fko];
  f32x4 a1[4] = {};
#pragma unroll
  for (int mb = 0; mb < 4; ++mb)
#pragma unroll
    for (int ks = 0; ks < 2; ++ks) {
      bf16x8 kf = *(const bf16x8*)&Ks[16 * mb + fr][32 * ks + fko];
      a1[mb] = __builtin_amdgcn_mfma_f32_16x16x32_bf16(qa[ks], kf, a1[mb], 0, 0, 0);
    }
#pragma unroll
  for (int i = 0; i < 4; ++i) {
    int n = 16 * w + 4 * g + i;
    ushort4 qv4 = *(const ushort4*)&Qs[n][fr * 4];
    float4  zv4 = *(const float4*)&zs[fr * 4];
    float rs = bf2f(qv4.x) * zv4.x + bf2f(qv4.y) * zv4.y +
               bf2f(qv4.z) * zv4.z + bf2f(qv4.w) * zv4.w;
#pragma unroll
    for (int mb = 0; mb < 4; ++mb) {
      int m = 16 * mb + fr;
      float v = (m <= n) ? a1[mb][i] : 0.f;
      a1[mb][i] = v;
      rs += v;
      Ams[n][16 * mb + fr] = f2bf(v);
    }
#pragma unroll
    for (int off = 1; off <= 8; off <<= 1) rs += __shfl_xor(rs, off);
    if (fr == 0) denom[n] = rs + 1.25e-7f;   // eps * sum(q) = 1e-6 * 0.125
  }
  __syncthreads();

  // step 2: O^T[e'][n] = Vt·A + St·Q
  bf16x8 xa[4];
#pragma unroll
  for (int ks = 0; ks < 2; ++ks) {
    xa[ks]     = *(const bf16x8*)&Vts[16 * w + fr][32 * ks + fko];
    xa[2 + ks] = *(const bf16x8*)&Sts[16 * w + fr][32 * ks + fko];
  }
  f32x4 o4[4] = {};
#pragma unroll
  for (int nb = 0; nb < 4; ++nb)
#pragma unroll
    for (int ks = 0; ks < 2; ++ks) {
      bf16x8 afr = *(const bf16x8*)&Ams[16 * nb + fr][32 * ks + fko];
      o4[nb] = __builtin_amdgcn_mfma_f32_16x16x32_bf16(xa[ks], afr, o4[nb], 0, 0, 0);
      bf16x8 qfr = *(const bf16x8*)&Qs[16 * nb + fr][32 * ks + fko];
      o4[nb] = __builtin_amdgcn_mfma_f32_16x16x32_bf16(xa[2 + ks], qfr, o4[nb], 0, 0, 0);
    }
#pragma unroll
  for (int nb = 0; nb < 4; ++nb) {
    int n = 16 * nb + fr;
    float dv = denom[n];
    float4 res = { o4[nb][0] / dv, o4[nb][1] / dv, o4[nb][2] / dv, o4[nb][3] / dv };
    *(float4*)&out[(size_t)(c * 64 + n) * 1024 + h * 64 + 16 * w + 4 * g] = res;
  }
}

extern "C" void kernel_launch(void* const* d_in, const int* in_sizes, int n_in,
                              void* d_out, int out_size, void* d_ws, size_t ws_size,
                              hipStream_t stream) {
  (void)in_sizes; (void)n_in; (void)out_size; (void)ws_size;
  const float* x = (const float*)d_in[0];
  const float* W = (const float*)d_in[1];
  const float* b = (const float*)d_in[2];
  char* ws = (char*)d_ws;

  const size_t MB = 1024 * 1024;
  unsigned short* xb = (unsigned short*)(ws + 0);        // 4 MB
  unsigned short* Wt = (unsigned short*)(ws + 4 * MB);   // 6 MB
  unsigned short* qh = (unsigned short*)(ws + 10 * MB);  // 4 MB
  unsigned short* kh = (unsigned short*)(ws + 14 * MB);  // 4 MB
  unsigned short* vt = (unsigned short*)(ws + 18 * MB);  // 4 MB
  unsigned short* Sc = (unsigned short*)(ws + 22 * MB);  // 4 MB (bf16 chunk sums)
  unsigned short* Sp = (unsigned short*)(ws + 26 * MB);  // 4 MB (bf16 exclusive prefix)
  float*          zc = (float*)(ws + 30 * MB);           // 128 KB
  float*          zp = (float*)(ws + 30 * MB + 131072);  // 128 KB

  k_prep_inputs<<<dim3(5120), dim3(256), 0, stream>>>(x, xb, W, Wt);
  k_gemm_fused<<<dim3(16, 16), dim3(768), 0, stream>>>(xb, Wt, b, qh, kh, vt, Sc, zc);
  k_scan<<<dim3(257), dim3(256), 0, stream>>>(Sc, Sp, zc, zp);
  k_attn<<<dim3(512), dim3(256), 0, stream>>>(qh, kh, vt, Sp, zp, (float*)d_out);
}